// Round 7
// baseline (452.703 us; speedup 1.0000x reference)
//
#include <hip/hip_runtime.h>
#include <hip/hip_bf16.h>

// Problem constants
constexpr int B_ = 8;
constexpr int L_ = 2048;
constexpr int C_ = 512;
constexpr int R_ = 64;
constexpr int DK_ = 64;
constexpr int H_ = 1024;   // 2*C
constexpr int M_ = B_ * L_;  // 16384
constexpr float NEG_ = -32767.0f;

__device__ __forceinline__ float toF(float x) { return x; }
__device__ __forceinline__ float toF(__hip_bfloat16 x) { return __bfloat162float(x); }
__device__ __forceinline__ float siluf(float v) { return v / (1.0f + __expf(-v)); }
__device__ __forceinline__ ushort bfbits(float f) {
    __hip_bfloat16 h = __float2bfloat16(f);
    union { __hip_bfloat16 h; ushort u; } cv; cv.h = h; return cv.u;
}
__device__ __forceinline__ float bf2f(ushort u) {
    union { uint u; float f; } cv; cv.u = (uint)u << 16; return cv.f;
}

typedef __attribute__((ext_vector_type(8))) short bf16x8;   // 8 bf16 (4 VGPRs)
typedef __attribute__((ext_vector_type(4))) float f32x4;    // 4 fp32 acc

// ---------------------------------------------------------------------------
// MFMA bf16 GEMM, 128x128 block tile, BK=32, 4 waves = 2x2 of 64x64 wave
// tiles, mfma_f32_16x16x32_bf16, 4x4 subtiles/wave, register-prefetch
// pipelined staging (next tile's global loads issued before the MFMA phase).
// XCD-aware 1-D swizzle: block i -> xcd i&7; per-XCD m-major, n fastest.
// AF32: A operand is fp32 in global, converted to bf16 during LDS staging.
// EPI 0: silu(acc + bias[n])                   -> bf16
// EPI 1: acc + bias[n]; mask[row]==0 -> NEG    -> fp32 (pScore; Ndim=64<128,
//        col-guarded)
// EPI 2: acc + bias[n] + residF[m][n] (fp32)   -> bf16
// EPI 3: acc * residB[m][n] (bf16, in-place)   -> bf16 (no bias)
// bBatch: if nonzero, Bt += (m0/L_)*bBatch (batched B, expand GEMM).
// ---------------------------------------------------------------------------
template <int EPI, int AF32>
__global__ __launch_bounds__(256) void mfma_gemm3(
    const void* __restrict__ Ap, const ushort* __restrict__ Bt,
    const float* __restrict__ bias,
    const float* __restrict__ residF, const ushort* __restrict__ residB,
    const int* __restrict__ mask,
    ushort* __restrict__ outB, float* __restrict__ outF,
    int Ndim, int Kdim, int gridN, long bBatch)
{
    constexpr int LDA = 40;                 // row pad: 80 B, 16B-aligned b128 reads
    __shared__ ushort As[128 * LDA];
    __shared__ ushort Bs[128 * LDA];

    const int i = blockIdx.x;
    const int G = gridDim.x >> 3;           // blocks per XCD (grid % 8 == 0)
    const int gi = (i & 7) * G + (i >> 3);
    const int nt = gi % gridN, mt = gi / gridN;
    const int m0 = mt * 128, n0 = nt * 128;

    const int tid = threadIdx.x;
    const int lane = tid & 63, w = tid >> 6;
    const int wm = (w & 1) * 64, wn = (w >> 1) * 64;
    const int lr = lane & 15, lq = lane >> 4;
    const int srow = tid >> 2, scol = (tid & 3) * 8;   // 64 rows x 32 k per pass

    const float*  Af = (const float*)Ap;
    const ushort* Au = (const ushort*)Ap;
    const ushort* Bp = Bt + (bBatch ? (long)(m0 / L_) * bBatch : 0);
    // B row clamp for Ndim < 128 tiles (garbage cols masked at store)
    const int br0 = (n0 + srow      < Ndim) ? n0 + srow      : Ndim - 1;
    const int br1 = (n0 + 64 + srow < Ndim) ? n0 + 64 + srow : Ndim - 1;

    f32x4 acc[4][4];
#pragma unroll
    for (int a = 0; a < 4; ++a)
#pragma unroll
        for (int b = 0; b < 4; ++b) acc[a][b] = (f32x4){0.f, 0.f, 0.f, 0.f};

    uint4 pa[4], pb[2];
    auto loadTiles = [&](int k0) {
        if (AF32) {
            pa[0] = *(const uint4*)(Af + (size_t)(m0 + srow) * Kdim + k0 + scol);
            pa[1] = *(const uint4*)(Af + (size_t)(m0 + srow) * Kdim + k0 + scol + 4);
            pa[2] = *(const uint4*)(Af + (size_t)(m0 + 64 + srow) * Kdim + k0 + scol);
            pa[3] = *(const uint4*)(Af + (size_t)(m0 + 64 + srow) * Kdim + k0 + scol + 4);
        } else {
            pa[0] = *(const uint4*)(Au + (size_t)(m0 + srow) * Kdim + k0 + scol);
            pa[1] = *(const uint4*)(Au + (size_t)(m0 + 64 + srow) * Kdim + k0 + scol);
        }
        pb[0] = *(const uint4*)(Bp + (size_t)br0 * Kdim + k0 + scol);
        pb[1] = *(const uint4*)(Bp + (size_t)br1 * Kdim + k0 + scol);
    };
    auto storeLDS = [&]() {
        if (AF32) {
            const float* f0 = (const float*)&pa[0];   // pa[0],pa[1] contiguous 8 floats
            const float* f1 = (const float*)&pa[2];
            ushort t0[8], t1[8];
#pragma unroll
            for (int t = 0; t < 8; ++t) { t0[t] = bfbits(f0[t]); t1[t] = bfbits(f1[t]); }
            *(uint4*)&As[srow * LDA + scol] = *(const uint4*)t0;
            *(uint4*)&As[(64 + srow) * LDA + scol] = *(const uint4*)t1;
        } else {
            *(uint4*)&As[srow * LDA + scol] = pa[0];
            *(uint4*)&As[(64 + srow) * LDA + scol] = pa[1];
        }
        *(uint4*)&Bs[srow * LDA + scol] = pb[0];
        *(uint4*)&Bs[(64 + srow) * LDA + scol] = pb[1];
    };

    loadTiles(0);
    for (int k0 = 0; k0 < Kdim; k0 += 32) {
        __syncthreads();              // all waves done reading LDS (prev iter)
        storeLDS();                   // vmcnt wait folded in here by compiler
        __syncthreads();
        if (k0 + 32 < Kdim) loadTiles(k0 + 32);   // overlap with MFMA phase

        bf16x8 af[4], bf[4];
#pragma unroll
        for (int a = 0; a < 4; ++a)
            af[a] = *(const bf16x8*)&As[(wm + a * 16 + lr) * LDA + lq * 8];
#pragma unroll
        for (int b = 0; b < 4; ++b)
            bf[b] = *(const bf16x8*)&Bs[(wn + b * 16 + lr) * LDA + lq * 8];
#pragma unroll
        for (int a = 0; a < 4; ++a)
#pragma unroll
            for (int b = 0; b < 4; ++b)
                acc[a][b] = __builtin_amdgcn_mfma_f32_16x16x32_bf16(af[a], bf[b], acc[a][b], 0, 0, 0);
    }

#pragma unroll
    for (int a = 0; a < 4; ++a) {
#pragma unroll
        for (int b = 0; b < 4; ++b) {
            const int col = n0 + wn + b * 16 + lr;
            if (col < Ndim) {
                const float bn = (EPI == 3) ? 0.f : bias[col];
#pragma unroll
                for (int r = 0; r < 4; ++r) {
                    const int row = m0 + wm + a * 16 + lq * 4 + r;
                    float v = acc[a][b][r];
                    if (EPI == 0) {
                        v = siluf(v + bn);
                        outB[(size_t)row * Ndim + col] = bfbits(v);
                    } else if (EPI == 1) {
                        v += bn;
                        if (mask[row] == 0) v = NEG_;
                        outF[(size_t)row * Ndim + col] = v;
                    } else if (EPI == 2) {
                        v += bn + residF[(size_t)row * Ndim + col];
                        outB[(size_t)row * Ndim + col] = bfbits(v);
                    } else {
                        v *= bf2f(residB[(size_t)row * Ndim + col]);
                        outB[(size_t)row * Ndim + col] = bfbits(v);
                    }
                }
            }
        }
    }
}

// W[K,N] fp32 -> Wt[N,K] bf16 (32x32 LDS tiles)
__global__ __launch_bounds__(256) void transpose_to_bf16(
    const float* __restrict__ W, ushort* __restrict__ Wt, int K, int N)
{
    __shared__ float tile[32][33];
    const int tx = threadIdx.x & 31, ty = threadIdx.x >> 5;   // 32x8
    const int n0 = blockIdx.x * 32, k0 = blockIdx.y * 32;
#pragma unroll
    for (int i = 0; i < 32; i += 8)
        tile[ty + i][tx] = W[(size_t)(k0 + ty + i) * N + n0 + tx];
    __syncthreads();
#pragma unroll
    for (int i = 0; i < 32; i += 8)
        Wt[(size_t)(n0 + ty + i) * K + k0 + tx] = bfbits(tile[tx][ty + i]);
}

// ---------------------------------------------------------------------------
// SIMT 64x64 tiled GEMM (compact path only).
// ---------------------------------------------------------------------------
template <typename AT, typename BT, typename RT, int ACT, int EPI>
__global__ __launch_bounds__(256) void gemm64(
    const AT* __restrict__ A, const BT* __restrict__ Bw,
    const float* __restrict__ bias,
    const int* __restrict__ mask,
    const RT* resid,
    float* __restrict__ outF, __hip_bfloat16* outB,
    int Ndim, int Kdim, long bBatchStride)
{
    __shared__ float As[16][68];
    __shared__ float Bs[16][64];
    const int tid = threadIdx.x;
    const int tx = tid & 15, ty = tid >> 4;
    const int n0 = blockIdx.x * 64, m0 = blockIdx.y * 64;
    const BT* Bp = Bw + (bBatchStride ? (long)(m0 / L_) * bBatchStride : 0);

    float acc[4][4] = {};

    for (int k0 = 0; k0 < Kdim; k0 += 16) {
#pragma unroll
        for (int s = 0; s < 4; ++s) {
            int idx = tid + s * 256;
            int am = idx >> 4, ak = idx & 15;
            As[ak][am] = toF(A[(size_t)(m0 + am) * Kdim + k0 + ak]);
        }
#pragma unroll
        for (int s = 0; s < 4; ++s) {
            int idx = tid + s * 256;
            int bk = idx >> 6, bn = idx & 63;
            Bs[bk][bn] = toF(Bp[(size_t)(k0 + bk) * Ndim + n0 + bn]);
        }
        __syncthreads();
#pragma unroll
        for (int kk = 0; kk < 16; ++kk) {
            float av[4], bv[4];
            *(float4*)av = *(const float4*)&As[kk][ty * 4];
            *(float4*)bv = *(const float4*)&Bs[kk][tx * 4];
#pragma unroll
            for (int i = 0; i < 4; ++i)
#pragma unroll
                for (int j = 0; j < 4; ++j) acc[i][j] += av[i] * bv[j];
        }
        __syncthreads();
    }

#pragma unroll
    for (int i = 0; i < 4; ++i) {
        int m = m0 + ty * 4 + i;
#pragma unroll
        for (int j = 0; j < 4; ++j) {
            int n = n0 + tx * 4 + j;
            float val = acc[i][j];
            if (EPI != 3) val += bias[n];
            if (ACT) val = siluf(val);
            if (EPI == 0) {
                outB[(size_t)m * Ndim + n] = __float2bfloat16(val);
            } else if (EPI == 1) {
                if (mask[m] == 0) val = NEG_;
                outF[(size_t)m * Ndim + n] = val;
            } else if (EPI == 2) {
                val += toF(resid[(size_t)m * Ndim + n]);
                outB[(size_t)m * Ndim + n] = __float2bfloat16(val);
            } else {
                val *= toF(resid[(size_t)m * Ndim + n]);
                outB[(size_t)m * Ndim + n] = __float2bfloat16(val);
            }
        }
    }
}

// softmax over L (axis=1). One block per (b, r).
__global__ __launch_bounds__(256) void softmaxL(const float* __restrict__ pScore,
                                                float* __restrict__ pAlpha)
{
    const int b = blockIdx.x >> 6, r = blockIdx.x & 63;
    const int t = threadIdx.x;
    const float* base = pScore + (size_t)b * L_ * R_ + r;
    float* out = pAlpha + (size_t)b * L_ * R_ + r;
    __shared__ float red[256];

    float mx = -3.4e38f;
    for (int l = t; l < L_; l += 256) mx = fmaxf(mx, base[(size_t)l * R_]);
    red[t] = mx; __syncthreads();
    for (int s = 128; s > 0; s >>= 1) { if (t < s) red[t] = fmaxf(red[t], red[t + s]); __syncthreads(); }
    mx = red[0]; __syncthreads();

    float sum = 0.f;
    for (int l = t; l < L_; l += 256) {
        float e = __expf(base[(size_t)l * R_] - mx);
        out[(size_t)l * R_] = e;
        sum += e;
    }
    red[t] = sum; __syncthreads();
    for (int s = 128; s > 0; s >>= 1) { if (t < s) red[t] += red[t + s]; __syncthreads(); }
    const float inv = 1.0f / red[0];
    for (int l = t; l < L_; l += 256) out[(size_t)l * R_] *= inv;
}

// softmax over r (axis=-1). One wave per row m. OUT=0: fp32, OUT=1: bf16 bits.
template <int OUT>
__global__ __launch_bounds__(64) void softmaxR(const float* __restrict__ pScore,
                                               float* __restrict__ outF,
                                               ushort* __restrict__ outU)
{
    const size_t m = blockIdx.x;
    const int t = threadIdx.x;
    float v = pScore[m * R_ + t];
    float mx = v;
#pragma unroll
    for (int o = 32; o > 0; o >>= 1) mx = fmaxf(mx, __shfl_xor(mx, o, 64));
    float e = __expf(v - mx);
    float s = e;
#pragma unroll
    for (int o = 32; o > 0; o >>= 1) s += __shfl_xor(s, o, 64);
    if (OUT == 0) outF[m * R_ + t] = e / s;
    else          outU[m * R_ + t] = bfbits(e / s);
}

// compress K-split GEMM parts
__global__ __launch_bounds__(256) void compress_part(
    const float* __restrict__ pAlpha, const float* __restrict__ x,
    float* __restrict__ parts)
{
    __shared__ float As[16][64];
    __shared__ float Bs[16][64];
    const int tid = threadIdx.x;
    const int tx = tid & 15, ty = tid >> 4;
    const int n0 = blockIdx.x * 64;
    const int ks = blockIdx.y;
    const int b  = blockIdx.z;
    const float* pa = pAlpha + (size_t)b * L_ * R_;
    const float* xb = x + (size_t)b * L_ * C_;
    float acc[4][4] = {};
    const int kbeg = ks * (L_ / 4), kend = kbeg + L_ / 4;
    for (int k0 = kbeg; k0 < kend; k0 += 16) {
#pragma unroll
        for (int s = 0; s < 4; ++s) {
            int idx = tid + s * 256;
            int kk = idx >> 6, m = idx & 63;
            As[kk][m] = pa[(size_t)(k0 + kk) * R_ + m];
        }
#pragma unroll
        for (int s = 0; s < 4; ++s) {
            int idx = tid + s * 256;
            int kk = idx >> 6, n = idx & 63;
            Bs[kk][n] = xb[(size_t)(k0 + kk) * C_ + n0 + n];
        }
        __syncthreads();
#pragma unroll
        for (int kk = 0; kk < 16; ++kk) {
            float av[4], bv[4];
            *(float4*)av = *(const float4*)&As[kk][ty * 4];
            *(float4*)bv = *(const float4*)&Bs[kk][tx * 4];
#pragma unroll
            for (int i = 0; i < 4; ++i)
#pragma unroll
                for (int j = 0; j < 4; ++j) acc[i][j] += av[i] * bv[j];
        }
        __syncthreads();
    }
#pragma unroll
    for (int i = 0; i < 4; ++i)
#pragma unroll
        for (int j = 0; j < 4; ++j)
            parts[((((size_t)ks * B_ + b) * R_) + ty * 4 + i) * C_ + n0 + tx * 4 + j] = acc[i][j];
}

__global__ __launch_bounds__(256) void compress_reduce(const float* __restrict__ parts,
                                                       float* __restrict__ px)
{
    const size_t i = (size_t)blockIdx.x * 256 + threadIdx.x;
    constexpr size_t S = (size_t)B_ * R_ * C_;
    px[i] = parts[i] + parts[i + S] + parts[i + 2 * S] + parts[i + 3 * S];
}

// qkv fused-N GEMM
__global__ __launch_bounds__(256) void qkv_gemm(
    const float* __restrict__ px,
    const float* __restrict__ Wq, const float* __restrict__ bq,
    const float* __restrict__ Wk, const float* __restrict__ bk,
    const float* __restrict__ Wv, const float* __restrict__ bv,
    float* __restrict__ q, float* __restrict__ k, float* __restrict__ v)
{
    __shared__ float As[16][68];
    __shared__ float Bs[16][64];
    const int tid = threadIdx.x;
    const int tx = tid & 15, ty = tid >> 4;
    const int bx = blockIdx.x;
    const int m0 = blockIdx.y * 64;
    const float* W; const float* bias; float* dst; int Nloc, ncol0;
    if (bx == 0)      { W = Wq; bias = bq; dst = q; Nloc = 64;   ncol0 = 0; }
    else if (bx == 1) { W = Wk; bias = bk; dst = k; Nloc = 64;   ncol0 = 0; }
    else              { W = Wv; bias = bv; dst = v; Nloc = H_;   ncol0 = (bx - 2) * 64; }

    float acc[4][4] = {};
    for (int k0 = 0; k0 < C_; k0 += 16) {
#pragma unroll
        for (int s = 0; s < 4; ++s) {
            int idx = tid + s * 256;
            int am = idx >> 4, ak = idx & 15;
            As[ak][am] = px[(size_t)(m0 + am) * C_ + k0 + ak];
        }
#pragma unroll
        for (int s = 0; s < 4; ++s) {
            int idx = tid + s * 256;
            int kk = idx >> 6, bn = idx & 63;
            Bs[kk][bn] = W[(size_t)(k0 + kk) * Nloc + ncol0 + bn];
        }
        __syncthreads();
#pragma unroll
        for (int kk = 0; kk < 16; ++kk) {
            float av[4], bv4[4];
            *(float4*)av = *(const float4*)&As[kk][ty * 4];
            *(float4*)bv4 = *(const float4*)&Bs[kk][tx * 4];
#pragma unroll
            for (int i = 0; i < 4; ++i)
#pragma unroll
                for (int j = 0; j < 4; ++j) acc[i][j] += av[i] * bv4[j];
        }
        __syncthreads();
    }
#pragma unroll
    for (int i = 0; i < 4; ++i) {
        int m = m0 + ty * 4 + i;
#pragma unroll
        for (int j = 0; j < 4; ++j) {
            int n = ncol0 + tx * 4 + j;
            dst[(size_t)m * Nloc + n] = siluf(acc[i][j] + bias[n]);
        }
    }
}

// scores + softmax -> alpha
__global__ __launch_bounds__(64) void attn_scores(
    const float* __restrict__ q, const float* __restrict__ k,
    const float* __restrict__ preS, float* __restrict__ alpha)
{
    const int b = blockIdx.x >> 6, r = blockIdx.x & 63;
    const int s = threadIdx.x;
    const float* qr = q + ((size_t)b * R_ + r) * DK_;
    const float* ks = k + ((size_t)b * R_ + s) * DK_;
    float acc = 0.f;
#pragma unroll
    for (int d = 0; d < DK_; ++d) acc += qr[d] * ks[d];
    acc = acc * 0.125f + preS[((size_t)b * R_ + r) * R_ + s];
    float mx = acc;
#pragma unroll
    for (int o = 32; o > 0; o >>= 1) mx = fmaxf(mx, __shfl_xor(mx, o, 64));
    float e = __expf(acc - mx);
    float sm = e;
#pragma unroll
    for (int o = 32; o > 0; o >>= 1) sm += __shfl_xor(sm, o, 64);
    alpha[((size_t)b * R_ + r) * R_ + s] = e / sm;
}

// z_small = alpha @ v.  MODE 0: zs fp32 [b][r][h]; MODE 1: zsT bf16 [b][h][r].
template <int MODE>
__global__ __launch_bounds__(256) void attn_z(const float* __restrict__ alpha,
                                              const float* __restrict__ v,
                                              float* __restrict__ zsF,
                                              ushort* __restrict__ zsT)
{
    const int b = blockIdx.x >> 6, r = blockIdx.x & 63;
    const int t = threadIdx.x;
    __shared__ float al[R_];
    if (t < R_) al[t] = alpha[((size_t)b * R_ + r) * R_ + t];
    __syncthreads();
    float acc[4] = {};
    for (int s = 0; s < R_; ++s) {
        float a = al[s];
        const float* vr = v + ((size_t)b * R_ + s) * H_;
#pragma unroll
        for (int j = 0; j < 4; ++j) acc[j] += a * vr[t + j * 256];
    }
#pragma unroll
    for (int j = 0; j < 4; ++j) {
        const int h = t + j * 256;
        if (MODE == 0) zsF[((size_t)b * R_ + r) * H_ + h] = acc[j];
        else           zsT[((size_t)b * H_ + h) * R_ + r] = bfbits(acc[j]);
    }
}

// Row layernorm of bf16 y -> fp32 out
__global__ __launch_bounds__(256) void layernorm(const __hip_bfloat16* __restrict__ y,
                                                 const float* __restrict__ gamma,
                                                 const float* __restrict__ beta,
                                                 float* __restrict__ out)
{
    const size_t m = blockIdx.x;
    const int t = threadIdx.x;
    const __hip_bfloat16* yr = y + m * C_;
    float v0 = __bfloat162float(yr[t]), v1 = __bfloat162float(yr[t + 256]);
    __shared__ float rs[256], rq[256];
    rs[t] = v0 + v1;
    rq[t] = v0 * v0 + v1 * v1;
    __syncthreads();
    for (int o = 128; o > 0; o >>= 1) {
        if (t < o) { rs[t] += rs[t + o]; rq[t] += rq[t + o]; }
        __syncthreads();
    }
    const float mu = rs[0] * (1.0f / C_);
    const float var = rq[0] * (1.0f / C_) - mu * mu;
    const float inv = rsqrtf(var + 1e-5f);
    out[m * C_ + t] = (v0 - mu) * inv * gamma[t] + beta[t];
    out[m * C_ + t + 256] = (v1 - mu) * inv * gamma[t + 256] + beta[t + 256];
}

extern "C" void kernel_launch(void* const* d_in, const int* in_sizes, int n_in,
                              void* d_out, int out_size, void* d_ws, size_t ws_size,
                              hipStream_t stream)
{
    using bf16 = __hip_bfloat16;
    const float* x      = (const float*)d_in[0];
    const int*  maskPAD = (const int*)d_in[1];
    const float* preS   = (const float*)d_in[2];
    const float* Wp     = (const float*)d_in[3];
    const float* bp     = (const float*)d_in[4];
    const float* Wq     = (const float*)d_in[5];
    const float* bq     = (const float*)d_in[6];
    const float* Wk     = (const float*)d_in[7];
    const float* bk     = (const float*)d_in[8];
    const float* Wv     = (const float*)d_in[9];
    const float* bv     = (const float*)d_in[10];
    const float* Wu     = (const float*)d_in[11];
    const float* bu     = (const float*)d_in[12];
    const float* Wo     = (const float*)d_in[13];
    const float* bo     = (const float*)d_in[14];
    const float* gamma  = (const float*)d_in[15];
    const float* beta   = (const float*)d_in[16];
    float* out          = (float*)d_out;

    char* ws = (char*)d_ws;
    const bool bigWS = ws_size >= (size_t)52 * 1024 * 1024;  // proven taken (rounds 4-6)

    if (bigWS) {
        // layout: gate 33.5 MB | pool 18.2 MB | Wut 1 MB | Wot 1 MB | Wpt 64 KB
        bf16* gate = (bf16*)ws;                                 // M*H bf16 (zg in-place later)
        char* pool = ws + (size_t)M_ * H_ * 2;
        float* pScore = (float*)pool;                           // reused: compress parts
        float* pAL   = pScore + (size_t)M_ * R_;
        float* pAR   = pAL    + (size_t)M_ * R_;                // bf16 (pAR16)
        float* px    = pAR    + (size_t)M_ * R_;
        float* q     = px     + (size_t)B_ * R_ * C_;
        float* kk    = q      + (size_t)B_ * R_ * DK_;
        float* vv    = kk     + (size_t)B_ * R_ * DK_;
        float* alpha = vv     + (size_t)B_ * R_ * H_;
        float* zs    = alpha  + (size_t)B_ * R_ * R_;           // bf16 zsT [B,H,R]
        ushort* pAR16 = (ushort*)pAR;
        ushort* zsT16 = (ushort*)zs;
        bf16*  y     = (bf16*)pool;                             // pre-LN y, aliases dead pool
        ushort* Wut  = (ushort*)(pool + 18221568);              // [H, C] bf16
        ushort* Wot  = Wut + (size_t)C_ * H_;                   // [C, H] bf16
        ushort* Wpt  = Wot + (size_t)C_ * H_;                   // [R, C] bf16

        // prep transposes
        transpose_to_bf16<<<dim3(H_ / 32, C_ / 32), 256, 0, stream>>>(Wu, Wut, C_, H_);
        transpose_to_bf16<<<dim3(C_ / 32, H_ / 32), 256, 0, stream>>>(Wo, Wot, H_, C_);
        transpose_to_bf16<<<dim3(R_ / 32, C_ / 32), 256, 0, stream>>>(Wp, Wpt, C_, R_);

        // 1) gate = silu(x @ Wu + bu)  [MFMA, fp32 A on-the-fly]
        mfma_gemm3<0, 1><<<(H_ / 128) * (M_ / 128), 256, 0, stream>>>(
            x, Wut, bu, nullptr, nullptr, nullptr, (ushort*)gate, nullptr,
            H_, C_, H_ / 128, 0);
        // 2) pScore = x @ Wp + bp, mask  [MFMA, N=64 col-guarded]
        mfma_gemm3<1, 1><<<1 * (M_ / 128), 256, 0, stream>>>(
            x, Wpt, bp, nullptr, nullptr, maskPAD, nullptr, pScore,
            R_, C_, 1, 0);
        softmaxL<<<B_ * R_, 256, 0, stream>>>(pScore, pAL);
        softmaxR<1><<<M_, 64, 0, stream>>>(pScore, nullptr, pAR16);
        compress_part<<<dim3(C_ / 64, 4, B_), 256, 0, stream>>>(pAL, x, pScore);
        compress_reduce<<<(B_ * R_ * C_) / 256, 256, 0, stream>>>(pScore, px);
        qkv_gemm<<<dim3(2 + H_ / 64, (B_ * R_) / 64), 256, 0, stream>>>(
            px, Wq, bq, Wk, bk, Wv, bv, q, kk, vv);
        attn_scores<<<B_ * R_, 64, 0, stream>>>(q, kk, preS, alpha);
        attn_z<1><<<B_ * R_, 256, 0, stream>>>(alpha, vv, nullptr, zsT16);
        // 9) zg = gate * (pAR @ zs)  [MFMA K=64, batched B, in-place]
        mfma_gemm3<3, 0><<<(H_ / 128) * (M_ / 128), 256, 0, stream>>>(
            pAR16, zsT16, nullptr, nullptr, (ushort*)gate, nullptr, (ushort*)gate,
            nullptr, H_, R_, H_ / 128, (long)H_ * R_);
        // 10) y = x + zg @ Wo + bo  [MFMA, fp32 residual]
        mfma_gemm3<2, 0><<<(C_ / 128) * (M_ / 128), 256, 0, stream>>>(
            (ushort*)gate, Wot, bo, x, nullptr, nullptr, (ushort*)y, nullptr,
            C_, H_, C_ / 128, 0);
        layernorm<<<M_, 256, 0, stream>>>(y, gamma, beta, out);
    } else {
        // ---- Compact plan (~23.4 MiB), SIMT per-batch (dead in practice) ----
        float* pScore = (float*)ws;
        float* pAL   = pScore + (size_t)M_ * R_;
        float* pAR   = pAL    + (size_t)M_ * R_;
        float* px    = pAR    + (size_t)M_ * R_;
        float* q     = px     + (size_t)B_ * R_ * C_;
        float* kk    = q      + (size_t)B_ * R_ * DK_;
        float* vv    = kk     + (size_t)B_ * R_ * DK_;
        float* alpha = vv     + (size_t)B_ * R_ * H_;
        float* zs    = alpha  + (size_t)B_ * R_ * R_;
        bf16* gate_b = (bf16*)(zs + (size_t)B_ * R_ * H_);
        bf16* y_b    = (bf16*)((char*)gate_b + (size_t)L_ * H_ * 2);

        gemm64<float, float, float, 0, 1><<<dim3(R_ / 64, M_ / 64), 256, 0, stream>>>(
            x, Wp, bp, maskPAD, (const float*)nullptr, pScore, nullptr, R_, C_, 0);
        softmaxL<<<B_ * R_, 256, 0, stream>>>(pScore, pAL);
        softmaxR<0><<<M_, 64, 0, stream>>>(pScore, pAR, nullptr);
        compress_part<<<dim3(C_ / 64, 4, B_), 256, 0, stream>>>(pAL, x, pScore);
        compress_reduce<<<(B_ * R_ * C_) / 256, 256, 0, stream>>>(pScore, px);
        qkv_gemm<<<dim3(2 + H_ / 64, (B_ * R_) / 64), 256, 0, stream>>>(
            px, Wq, bq, Wk, bk, Wv, bv, q, kk, vv);
        attn_scores<<<B_ * R_, 64, 0, stream>>>(q, kk, preS, alpha);
        attn_z<0><<<B_ * R_, 256, 0, stream>>>(alpha, vv, zs, nullptr);

        for (int b = 0; b < B_; ++b) {
            const float* xb = x + (size_t)b * L_ * C_;
            gemm64<float, float, float, 1, 0><<<dim3(H_ / 64, L_ / 64), 256, 0, stream>>>(
                xb, Wu, bu, nullptr, (const float*)nullptr, nullptr, gate_b, H_, C_, 0);
            gemm64<float, float, bf16, 0, 3><<<dim3(H_ / 64, L_ / 64), 256, 0, stream>>>(
                pAR + (size_t)b * L_ * R_, zs + (size_t)b * R_ * H_,
                nullptr, nullptr, gate_b, nullptr, gate_b, H_, R_, 0);
            gemm64<bf16, float, float, 0, 2><<<dim3(C_ / 64, L_ / 64), 256, 0, stream>>>(
                gate_b, Wo, bo, nullptr, xb, nullptr, y_b, C_, H_, 0);
            layernorm<<<L_, 256, 0, stream>>>(y_b, gamma, beta, out + (size_t)b * L_ * C_);
        }
    }
}

// Round 8
// 362.897 us; speedup vs baseline: 1.2475x; 1.2475x over previous
//
#include <hip/hip_runtime.h>
#include <hip/hip_bf16.h>

// Problem constants
constexpr int B_ = 8;
constexpr int L_ = 2048;
constexpr int C_ = 512;
constexpr int R_ = 64;
constexpr int DK_ = 64;
constexpr int H_ = 1024;   // 2*C
constexpr int M_ = B_ * L_;  // 16384
constexpr float NEG_ = -32767.0f;

__device__ __forceinline__ float toF(float x) { return x; }
__device__ __forceinline__ float toF(__hip_bfloat16 x) { return __bfloat162float(x); }
__device__ __forceinline__ float siluf(float v) { return v / (1.0f + __expf(-v)); }
__device__ __forceinline__ ushort bfbits(float f) {
    __hip_bfloat16 h = __float2bfloat16(f);
    union { __hip_bfloat16 h; ushort u; } cv; cv.h = h; return cv.u;
}
__device__ __forceinline__ float bf2f(ushort u) {
    union { uint u; float f; } cv; cv.u = (uint)u << 16; return cv.f;
}

typedef __attribute__((ext_vector_type(8))) short bf16x8;   // 8 bf16 (4 VGPRs)
typedef __attribute__((ext_vector_type(4))) float f32x4;    // 4 fp32 acc

#define GLOBAL_AS __attribute__((address_space(1)))
#define LDS_AS    __attribute__((address_space(3)))
__device__ __forceinline__ void glds16(const ushort* g, ushort* l) {
    __builtin_amdgcn_global_load_lds((const GLOBAL_AS void*)g, (LDS_AS void*)l, 16, 0, 0);
}

// ---------------------------------------------------------------------------
// MFMA bf16 GEMM, 128x128 tile, BK=32, 4 waves = 2x2 of 64x64 wave tiles,
// mfma_f32_16x16x32_bf16, 4x4 subtiles/wave.  Staging via
// global_load_lds width=16 (m97 structure): no staging VGPRs, no VALU
// repack; LDS tiles UNPADDED [128][32] bf16 (lane i -> base + i*16 exactly,
// the wave-uniform-base+lane*size contract).  2-barrier K-loop.
// XCD swizzle: block i -> xcd i&7; per-XCD m-major, n fastest.
// EPI 0: silu(acc + bias[n])                 -> bf16
// EPI 1: acc + bias[n]; mask[row]==0 -> NEG  -> fp32 (pScore, Ndim=64 guarded)
// EPI 2: acc + bias[n] + residF (fp32)       -> bf16
// EPI 3: acc * residB (bf16, in-place ok)    -> bf16 (no bias)
// bBatch: if nonzero, Bt += (m0/L_)*bBatch (batched B, expand GEMM).
// ---------------------------------------------------------------------------
template <int EPI>
__global__ __launch_bounds__(256) void mfma_gemm4(
    const ushort* __restrict__ A, const ushort* __restrict__ Bt,
    const float* __restrict__ bias,
    const float* __restrict__ residF, const ushort* __restrict__ residB,
    const int* __restrict__ mask,
    ushort* __restrict__ outB, float* __restrict__ outF,
    int Ndim, int Kdim, int gridN, long bBatch)
{
    __shared__ ushort As[128 * 32];   // 8 KB, unpadded
    __shared__ ushort Bs[128 * 32];   // 8 KB, unpadded

    const int i = blockIdx.x;
    const int G = gridDim.x >> 3;     // blocks per XCD (grid % 8 == 0)
    const int gi = (i & 7) * G + (i >> 3);
    const int nt = gi % gridN, mt = gi / gridN;
    const int m0 = mt * 128, n0 = nt * 128;

    const int tid = threadIdx.x;
    const int lane = tid & 63, w = tid >> 6;
    const int wm = (w & 1) * 64, wn = (w >> 1) * 64;
    const int lr = lane & 15, lq = lane >> 4;

    // staging: segment s covers rows [s*16, s*16+16); wave w does s=2w, 2w+1.
    // lane -> row s*16 + (lane>>2), bf16 col (lane&3)*8  (16 B per lane)
    const int sr = lane >> 2;
    const int sc = (lane & 3) * 8;
    const int s0 = w * 2, s1 = w * 2 + 1;

    const ushort* Bp = Bt + (bBatch ? (long)(m0 / L_) * bBatch : 0);
    int br0 = n0 + s0 * 16 + sr; if (br0 >= Ndim) br0 = Ndim - 1;   // clamp (N<128)
    int br1 = n0 + s1 * 16 + sr; if (br1 >= Ndim) br1 = Ndim - 1;
    const ushort* a0p = A  + (size_t)(m0 + s0 * 16 + sr) * Kdim + sc;
    const ushort* a1p = A  + (size_t)(m0 + s1 * 16 + sr) * Kdim + sc;
    const ushort* b0p = Bp + (size_t)br0 * Kdim + sc;
    const ushort* b1p = Bp + (size_t)br1 * Kdim + sc;
    ushort* la0 = As + s0 * 512 + lane * 8;
    ushort* la1 = As + s1 * 512 + lane * 8;
    ushort* lb0 = Bs + s0 * 512 + lane * 8;
    ushort* lb1 = Bs + s1 * 512 + lane * 8;

    f32x4 acc[4][4];
#pragma unroll
    for (int a = 0; a < 4; ++a)
#pragma unroll
        for (int b = 0; b < 4; ++b) acc[a][b] = (f32x4){0.f, 0.f, 0.f, 0.f};

    for (int k0 = 0; k0 < Kdim; k0 += 32) {
        __syncthreads();              // prev iteration's LDS reads complete
        glds16(a0p + k0, la0);
        glds16(a1p + k0, la1);
        glds16(b0p + k0, lb0);
        glds16(b1p + k0, lb1);
        __syncthreads();              // vmcnt(0) drain + barrier (compiler)

        bf16x8 af[4], bf[4];
#pragma unroll
        for (int a = 0; a < 4; ++a)
            af[a] = *(const bf16x8*)&As[(wm + a * 16 + lr) * 32 + lq * 8];
#pragma unroll
        for (int b = 0; b < 4; ++b)
            bf[b] = *(const bf16x8*)&Bs[(wn + b * 16 + lr) * 32 + lq * 8];
#pragma unroll
        for (int a = 0; a < 4; ++a)
#pragma unroll
            for (int b = 0; b < 4; ++b)
                acc[a][b] = __builtin_amdgcn_mfma_f32_16x16x32_bf16(af[a], bf[b], acc[a][b], 0, 0, 0);
    }

#pragma unroll
    for (int a = 0; a < 4; ++a) {
#pragma unroll
        for (int b = 0; b < 4; ++b) {
            const int col = n0 + wn + b * 16 + lr;
            if (col < Ndim) {
                const float bn = (EPI == 3) ? 0.f : bias[col];
#pragma unroll
                for (int r = 0; r < 4; ++r) {
                    const int row = m0 + wm + a * 16 + lq * 4 + r;
                    float v = acc[a][b][r];
                    if (EPI == 0) {
                        v = siluf(v + bn);
                        outB[(size_t)row * Ndim + col] = bfbits(v);
                    } else if (EPI == 1) {
                        v += bn;
                        if (mask[row] == 0) v = NEG_;
                        outF[(size_t)row * Ndim + col] = v;
                    } else if (EPI == 2) {
                        v += bn + residF[(size_t)row * Ndim + col];
                        outB[(size_t)row * Ndim + col] = bfbits(v);
                    } else {
                        v *= bf2f(residB[(size_t)row * Ndim + col]);
                        outB[(size_t)row * Ndim + col] = bfbits(v);
                    }
                }
            }
        }
    }
}

// x fp32 -> bf16, 4 elems/thread
__global__ __launch_bounds__(256) void f32_to_bf16_k(const float* __restrict__ in,
                                                     ushort* __restrict__ out)
{
    const size_t i = ((size_t)blockIdx.x * 256 + threadIdx.x) * 4;
    const float4 v = *(const float4*)(in + i);
    ushort4 o;
    o.x = bfbits(v.x); o.y = bfbits(v.y); o.z = bfbits(v.z); o.w = bfbits(v.w);
    *(ushort4*)(out + i) = o;
}

// W[K,N] fp32 -> Wt[N,K] bf16 (32x32 LDS tiles)
__global__ __launch_bounds__(256) void transpose_to_bf16(
    const float* __restrict__ W, ushort* __restrict__ Wt, int K, int N)
{
    __shared__ float tile[32][33];
    const int tx = threadIdx.x & 31, ty = threadIdx.x >> 5;   // 32x8
    const int n0 = blockIdx.x * 32, k0 = blockIdx.y * 32;
#pragma unroll
    for (int i = 0; i < 32; i += 8)
        tile[ty + i][tx] = W[(size_t)(k0 + ty + i) * N + n0 + tx];
    __syncthreads();
#pragma unroll
    for (int i = 0; i < 32; i += 8)
        Wt[(size_t)(n0 + ty + i) * K + k0 + tx] = bfbits(tile[tx][ty + i]);
}

// ---------------------------------------------------------------------------
// SIMT 64x64 tiled GEMM (compact path only).
// ---------------------------------------------------------------------------
template <typename AT, typename BT, typename RT, int ACT, int EPI>
__global__ __launch_bounds__(256) void gemm64(
    const AT* __restrict__ A, const BT* __restrict__ Bw,
    const float* __restrict__ bias,
    const int* __restrict__ mask,
    const RT* resid,
    float* __restrict__ outF, __hip_bfloat16* outB,
    int Ndim, int Kdim, long bBatchStride)
{
    __shared__ float As[16][68];
    __shared__ float Bs[16][64];
    const int tid = threadIdx.x;
    const int tx = tid & 15, ty = tid >> 4;
    const int n0 = blockIdx.x * 64, m0 = blockIdx.y * 64;
    const BT* Bp = Bw + (bBatchStride ? (long)(m0 / L_) * bBatchStride : 0);

    float acc[4][4] = {};

    for (int k0 = 0; k0 < Kdim; k0 += 16) {
#pragma unroll
        for (int s = 0; s < 4; ++s) {
            int idx = tid + s * 256;
            int am = idx >> 4, ak = idx & 15;
            As[ak][am] = toF(A[(size_t)(m0 + am) * Kdim + k0 + ak]);
        }
#pragma unroll
        for (int s = 0; s < 4; ++s) {
            int idx = tid + s * 256;
            int bk = idx >> 6, bn = idx & 63;
            Bs[bk][bn] = toF(Bp[(size_t)(k0 + bk) * Ndim + n0 + bn]);
        }
        __syncthreads();
#pragma unroll
        for (int kk = 0; kk < 16; ++kk) {
            float av[4], bv[4];
            *(float4*)av = *(const float4*)&As[kk][ty * 4];
            *(float4*)bv = *(const float4*)&Bs[kk][tx * 4];
#pragma unroll
            for (int i = 0; i < 4; ++i)
#pragma unroll
                for (int j = 0; j < 4; ++j) acc[i][j] += av[i] * bv[j];
        }
        __syncthreads();
    }

#pragma unroll
    for (int i = 0; i < 4; ++i) {
        int m = m0 + ty * 4 + i;
#pragma unroll
        for (int j = 0; j < 4; ++j) {
            int n = n0 + tx * 4 + j;
            float val = acc[i][j];
            if (EPI != 3) val += bias[n];
            if (ACT) val = siluf(val);
            if (EPI == 0) {
                outB[(size_t)m * Ndim + n] = __float2bfloat16(val);
            } else if (EPI == 1) {
                if (mask[m] == 0) val = NEG_;
                outF[(size_t)m * Ndim + n] = val;
            } else if (EPI == 2) {
                val += toF(resid[(size_t)m * Ndim + n]);
                outB[(size_t)m * Ndim + n] = __float2bfloat16(val);
            } else {
                val *= toF(resid[(size_t)m * Ndim + n]);
                outB[(size_t)m * Ndim + n] = __float2bfloat16(val);
            }
        }
    }
}

// softmax over L (axis=1). One block per (b, r).
__global__ __launch_bounds__(256) void softmaxL(const float* __restrict__ pScore,
                                                float* __restrict__ pAlpha)
{
    const int b = blockIdx.x >> 6, r = blockIdx.x & 63;
    const int t = threadIdx.x;
    const float* base = pScore + (size_t)b * L_ * R_ + r;
    float* out = pAlpha + (size_t)b * L_ * R_ + r;
    __shared__ float red[256];

    float mx = -3.4e38f;
    for (int l = t; l < L_; l += 256) mx = fmaxf(mx, base[(size_t)l * R_]);
    red[t] = mx; __syncthreads();
    for (int s = 128; s > 0; s >>= 1) { if (t < s) red[t] = fmaxf(red[t], red[t + s]); __syncthreads(); }
    mx = red[0]; __syncthreads();

    float sum = 0.f;
    for (int l = t; l < L_; l += 256) {
        float e = __expf(base[(size_t)l * R_] - mx);
        out[(size_t)l * R_] = e;
        sum += e;
    }
    red[t] = sum; __syncthreads();
    for (int s = 128; s > 0; s >>= 1) { if (t < s) red[t] += red[t + s]; __syncthreads(); }
    const float inv = 1.0f / red[0];
    for (int l = t; l < L_; l += 256) out[(size_t)l * R_] *= inv;
}

// softmax over r (axis=-1). One wave per row m. OUT=0: fp32, OUT=1: bf16 bits.
template <int OUT>
__global__ __launch_bounds__(64) void softmaxR(const float* __restrict__ pScore,
                                               float* __restrict__ outF,
                                               ushort* __restrict__ outU)
{
    const size_t m = blockIdx.x;
    const int t = threadIdx.x;
    float v = pScore[m * R_ + t];
    float mx = v;
#pragma unroll
    for (int o = 32; o > 0; o >>= 1) mx = fmaxf(mx, __shfl_xor(mx, o, 64));
    float e = __expf(v - mx);
    float s = e;
#pragma unroll
    for (int o = 32; o > 0; o >>= 1) s += __shfl_xor(s, o, 64);
    if (OUT == 0) outF[m * R_ + t] = e / s;
    else          outU[m * R_ + t] = bfbits(e / s);
}

// compress K-split GEMM parts
__global__ __launch_bounds__(256) void compress_part(
    const float* __restrict__ pAlpha, const float* __restrict__ x,
    float* __restrict__ parts)
{
    __shared__ float As[16][64];
    __shared__ float Bs[16][64];
    const int tid = threadIdx.x;
    const int tx = tid & 15, ty = tid >> 4;
    const int n0 = blockIdx.x * 64;
    const int ks = blockIdx.y;
    const int b  = blockIdx.z;
    const float* pa = pAlpha + (size_t)b * L_ * R_;
    const float* xb = x + (size_t)b * L_ * C_;
    float acc[4][4] = {};
    const int kbeg = ks * (L_ / 4), kend = kbeg + L_ / 4;
    for (int k0 = kbeg; k0 < kend; k0 += 16) {
#pragma unroll
        for (int s = 0; s < 4; ++s) {
            int idx = tid + s * 256;
            int kk = idx >> 6, m = idx & 63;
            As[kk][m] = pa[(size_t)(k0 + kk) * R_ + m];
        }
#pragma unroll
        for (int s = 0; s < 4; ++s) {
            int idx = tid + s * 256;
            int kk = idx >> 6, n = idx & 63;
            Bs[kk][n] = xb[(size_t)(k0 + kk) * C_ + n0 + n];
        }
        __syncthreads();
#pragma unroll
        for (int kk = 0; kk < 16; ++kk) {
            float av[4], bv[4];
            *(float4*)av = *(const float4*)&As[kk][ty * 4];
            *(float4*)bv = *(const float4*)&Bs[kk][tx * 4];
#pragma unroll
            for (int i = 0; i < 4; ++i)
#pragma unroll
                for (int j = 0; j < 4; ++j) acc[i][j] += av[i] * bv[j];
        }
        __syncthreads();
    }
#pragma unroll
    for (int i = 0; i < 4; ++i)
#pragma unroll
        for (int j = 0; j < 4; ++j)
            parts[((((size_t)ks * B_ + b) * R_) + ty * 4 + i) * C_ + n0 + tx * 4 + j] = acc[i][j];
}

__global__ __launch_bounds__(256) void compress_reduce(const float* __restrict__ parts,
                                                       float* __restrict__ px)
{
    const size_t i = (size_t)blockIdx.x * 256 + threadIdx.x;
    constexpr size_t S = (size_t)B_ * R_ * C_;
    px[i] = parts[i] + parts[i + S] + parts[i + 2 * S] + parts[i + 3 * S];
}

// qkv fused-N GEMM
__global__ __launch_bounds__(256) void qkv_gemm(
    const float* __restrict__ px,
    const float* __restrict__ Wq, const float* __restrict__ bq,
    const float* __restrict__ Wk, const float* __restrict__ bk,
    const float* __restrict__ Wv, const float* __restrict__ bv,
    float* __restrict__ q, float* __restrict__ k, float* __restrict__ v)
{
    __shared__ float As[16][68];
    __shared__ float Bs[16][64];
    const int tid = threadIdx.x;
    const int tx = tid & 15, ty = tid >> 4;
    const int bx = blockIdx.x;
    const int m0 = blockIdx.y * 64;
    const float* W; const float* bias; float* dst; int Nloc, ncol0;
    if (bx == 0)      { W = Wq; bias = bq; dst = q; Nloc = 64;   ncol0 = 0; }
    else if (bx == 1) { W = Wk; bias = bk; dst = k; Nloc = 64;   ncol0 = 0; }
    else              { W = Wv; bias = bv; dst = v; Nloc = H_;   ncol0 = (bx - 2) * 64; }

    float acc[4][4] = {};
    for (int k0 = 0; k0 < C_; k0 += 16) {
#pragma unroll
        for (int s = 0; s < 4; ++s) {
            int idx = tid + s * 256;
            int am = idx >> 4, ak = idx & 15;
            As[ak][am] = px[(size_t)(m0 + am) * C_ + k0 + ak];
        }
#pragma unroll
        for (int s = 0; s < 4; ++s) {
            int idx = tid + s * 256;
            int kk = idx >> 6, bn = idx & 63;
            Bs[kk][bn] = W[(size_t)(k0 + kk) * Nloc + ncol0 + bn];
        }
        __syncthreads();
#pragma unroll
        for (int kk = 0; kk < 16; ++kk) {
            float av[4], bv4[4];
            *(float4*)av = *(const float4*)&As[kk][ty * 4];
            *(float4*)bv4 = *(const float4*)&Bs[kk][tx * 4];
#pragma unroll
            for (int i = 0; i < 4; ++i)
#pragma unroll
                for (int j = 0; j < 4; ++j) acc[i][j] += av[i] * bv4[j];
        }
        __syncthreads();
    }
#pragma unroll
    for (int i = 0; i < 4; ++i) {
        int m = m0 + ty * 4 + i;
#pragma unroll
        for (int j = 0; j < 4; ++j) {
            int n = ncol0 + tx * 4 + j;
            dst[(size_t)m * Nloc + n] = siluf(acc[i][j] + bias[n]);
        }
    }
}

// scores + softmax -> alpha
__global__ __launch_bounds__(64) void attn_scores(
    const float* __restrict__ q, const float* __restrict__ k,
    const float* __restrict__ preS, float* __restrict__ alpha)
{
    const int b = blockIdx.x >> 6, r = blockIdx.x & 63;
    const int s = threadIdx.x;
    const float* qr = q + ((size_t)b * R_ + r) * DK_;
    const float* ks = k + ((size_t)b * R_ + s) * DK_;
    float acc = 0.f;
#pragma unroll
    for (int d = 0; d < DK_; ++d) acc += qr[d] * ks[d];
    acc = acc * 0.125f + preS[((size_t)b * R_ + r) * R_ + s];
    float mx = acc;
#pragma unroll
    for (int o = 32; o > 0; o >>= 1) mx = fmaxf(mx, __shfl_xor(mx, o, 64));
    float e = __expf(acc - mx);
    float sm = e;
#pragma unroll
    for (int o = 32; o > 0; o >>= 1) sm += __shfl_xor(sm, o, 64);
    alpha[((size_t)b * R_ + r) * R_ + s] = e / sm;
}

// z_small = alpha @ v.  MODE 0: zs fp32 [b][r][h]; MODE 1: zsT bf16 [b][h][r].
template <int MODE>
__global__ __launch_bounds__(256) void attn_z(const float* __restrict__ alpha,
                                              const float* __restrict__ v,
                                              float* __restrict__ zsF,
                                              ushort* __restrict__ zsT)
{
    const int b = blockIdx.x >> 6, r = blockIdx.x & 63;
    const int t = threadIdx.x;
    __shared__ float al[R_];
    if (t < R_) al[t] = alpha[((size_t)b * R_ + r) * R_ + t];
    __syncthreads();
    float acc[4] = {};
    for (int s = 0; s < R_; ++s) {
        float a = al[s];
        const float* vr = v + ((size_t)b * R_ + s) * H_;
#pragma unroll
        for (int j = 0; j < 4; ++j) acc[j] += a * vr[t + j * 256];
    }
#pragma unroll
    for (int j = 0; j < 4; ++j) {
        const int h = t + j * 256;
        if (MODE == 0) zsF[((size_t)b * R_ + r) * H_ + h] = acc[j];
        else           zsT[((size_t)b * H_ + h) * R_ + r] = bfbits(acc[j]);
    }
}

// Row layernorm of bf16 y -> fp32 out
__global__ __launch_bounds__(256) void layernorm(const __hip_bfloat16* __restrict__ y,
                                                 const float* __restrict__ gamma,
                                                 const float* __restrict__ beta,
                                                 float* __restrict__ out)
{
    const size_t m = blockIdx.x;
    const int t = threadIdx.x;
    const __hip_bfloat16* yr = y + m * C_;
    float v0 = __bfloat162float(yr[t]), v1 = __bfloat162float(yr[t + 256]);
    __shared__ float rs[256], rq[256];
    rs[t] = v0 + v1;
    rq[t] = v0 * v0 + v1 * v1;
    __syncthreads();
    for (int o = 128; o > 0; o >>= 1) {
        if (t < o) { rs[t] += rs[t + o]; rq[t] += rq[t + o]; }
        __syncthreads();
    }
    const float mu = rs[0] * (1.0f / C_);
    const float var = rq[0] * (1.0f / C_) - mu * mu;
    const float inv = rsqrtf(var + 1e-5f);
    out[m * C_ + t] = (v0 - mu) * inv * gamma[t] + beta[t];
    out[m * C_ + t + 256] = (v1 - mu) * inv * gamma[t + 256] + beta[t + 256];
}

extern "C" void kernel_launch(void* const* d_in, const int* in_sizes, int n_in,
                              void* d_out, int out_size, void* d_ws, size_t ws_size,
                              hipStream_t stream)
{
    using bf16 = __hip_bfloat16;
    const float* x      = (const float*)d_in[0];
    const int*  maskPAD = (const int*)d_in[1];
    const float* preS   = (const float*)d_in[2];
    const float* Wp     = (const float*)d_in[3];
    const float* bp     = (const float*)d_in[4];
    const float* Wq     = (const float*)d_in[5];
    const float* bq     = (const float*)d_in[6];
    const float* Wk     = (const float*)d_in[7];
    const float* bk     = (const float*)d_in[8];
    const float* Wv     = (const float*)d_in[9];
    const float* bv     = (const float*)d_in[10];
    const float* Wu     = (const float*)d_in[11];
    const float* bu     = (const float*)d_in[12];
    const float* Wo     = (const float*)d_in[13];
    const float* bo     = (const float*)d_in[14];
    const float* gamma  = (const float*)d_in[15];
    const float* beta   = (const float*)d_in[16];
    float* out          = (float*)d_out;

    char* ws = (char*)d_ws;
    const bool bigWS = ws_size >= (size_t)52 * 1024 * 1024;  // proven taken (rounds 4-7)

    if (bigWS) {
        // layout (51.4 MiB, proven): gate 33.5 MB | pool 18.2 MB | Wut | Wot | Wpt
        bf16* gate = (bf16*)ws;                                 // M*H bf16 (zg in-place later)
        char* pool = ws + (size_t)M_ * H_ * 2;
        float* pScore = (float*)pool;                           // reused: compress parts
        float* pAL   = pScore + (size_t)M_ * R_;
        float* pAR   = pAL    + (size_t)M_ * R_;                // bf16 (pAR16)
        float* px    = pAR    + (size_t)M_ * R_;
        float* q     = px     + (size_t)B_ * R_ * C_;
        float* kk    = q      + (size_t)B_ * R_ * DK_;
        float* vv    = kk     + (size_t)B_ * R_ * DK_;
        float* alpha = vv     + (size_t)B_ * R_ * H_;
        float* zs    = alpha  + (size_t)B_ * R_ * R_;           // bf16 zsT [B,H,R]
        ushort* pAR16 = (ushort*)pAR;
        ushort* zsT16 = (ushort*)zs;
        bf16*  y     = (bf16*)pool;                             // pre-LN y, aliases dead pool
        ushort* Wut  = (ushort*)(pool + 18221568);              // [H, C] bf16
        ushort* Wot  = Wut + (size_t)C_ * H_;                   // [C, H] bf16
        ushort* Wpt  = Wot + (size_t)C_ * H_;                   // [R, C] bf16
        // x16 lives in d_out (33.5 MB fp32 buffer; dead until layernorm)
        ushort* x16  = (ushort*)d_out;                          // [M, C] bf16

        // prep: x -> bf16 (into d_out); weight transposes
        f32_to_bf16_k<<<(M_ * C_) / 1024, 256, 0, stream>>>(x, x16);
        transpose_to_bf16<<<dim3(H_ / 32, C_ / 32), 256, 0, stream>>>(Wu, Wut, C_, H_);
        transpose_to_bf16<<<dim3(C_ / 32, H_ / 32), 256, 0, stream>>>(Wo, Wot, H_, C_);
        transpose_to_bf16<<<dim3(R_ / 32, C_ / 32), 256, 0, stream>>>(Wp, Wpt, C_, R_);

        // 1) gate = silu(x @ Wu + bu)  [MFMA + global_load_lds]
        mfma_gemm4<0><<<(H_ / 128) * (M_ / 128), 256, 0, stream>>>(
            x16, Wut, bu, nullptr, nullptr, nullptr, (ushort*)gate, nullptr,
            H_, C_, H_ / 128, 0);
        // 2) pScore = x @ Wp + bp, mask  [MFMA, N=64 guarded]
        mfma_gemm4<1><<<1 * (M_ / 128), 256, 0, stream>>>(
            x16, Wpt, bp, nullptr, nullptr, maskPAD, nullptr, pScore,
            R_, C_, 1, 0);
        softmaxL<<<B_ * R_, 256, 0, stream>>>(pScore, pAL);
        softmaxR<1><<<M_, 64, 0, stream>>>(pScore, nullptr, pAR16);
        compress_part<<<dim3(C_ / 64, 4, B_), 256, 0, stream>>>(pAL, x, pScore);
        compress_reduce<<<(B_ * R_ * C_) / 256, 256, 0, stream>>>(pScore, px);
        qkv_gemm<<<dim3(2 + H_ / 64, (B_ * R_) / 64), 256, 0, stream>>>(
            px, Wq, bq, Wk, bk, Wv, bv, q, kk, vv);
        attn_scores<<<B_ * R_, 64, 0, stream>>>(q, kk, preS, alpha);
        attn_z<1><<<B_ * R_, 256, 0, stream>>>(alpha, vv, nullptr, zsT16);
        // 9) zg = gate * (pAR @ zs)  [MFMA K=64, batched B, in-place]
        mfma_gemm4<3><<<(H_ / 128) * (M_ / 128), 256, 0, stream>>>(
            pAR16, zsT16, nullptr, nullptr, (ushort*)gate, nullptr, (ushort*)gate,
            nullptr, H_, R_, H_ / 128, (long)H_ * R_);
        // 10) y = x + zg @ Wo + bo  [MFMA, fp32 residual]
        mfma_gemm4<2><<<(C_ / 128) * (M_ / 128), 256, 0, stream>>>(
            (ushort*)gate, Wot, bo, x, nullptr, nullptr, (ushort*)y, nullptr,
            C_, H_, C_ / 128, 0);
        layernorm<<<M_, 256, 0, stream>>>(y, gamma, beta, out);
    } else {
        // ---- Compact plan (~23.4 MiB), SIMT per-batch (dead in practice) ----
        float* pScore = (float*)ws;
        float* pAL   = pScore + (size_t)M_ * R_;
        float* pAR   = pAL    + (size_t)M_ * R_;
        float* px    = pAR    + (size_t)M_ * R_;
        float* q     = px     + (size_t)B_ * R_ * C_;
        float* kk    = q      + (size_t)B_ * R_ * DK_;
        float* vv    = kk     + (size_t)B_ * R_ * DK_;
        float* alpha = vv     + (size_t)B_ * R_ * H_;
        float* zs    = alpha  + (size_t)B_ * R_ * R_;
        bf16* gate_b = (bf16*)(zs + (size_t)B_ * R_ * H_);
        bf16* y_b    = (bf16*)((char*)gate_b + (size_t)L_ * H_ * 2);

        gemm64<float, float, float, 0, 1><<<dim3(R_ / 64, M_ / 64), 256, 0, stream>>>(
            x, Wp, bp, maskPAD, (const float*)nullptr, pScore, nullptr, R_, C_, 0);
        softmaxL<<<B_ * R_, 256, 0, stream>>>(pScore, pAL);
        softmaxR<0><<<M_, 64, 0, stream>>>(pScore, pAR, nullptr);
        compress_part<<<dim3(C_ / 64, 4, B_), 256, 0, stream>>>(pAL, x, pScore);
        compress_reduce<<<(B_ * R_ * C_) / 256, 256, 0, stream>>>(pScore, px);
        qkv_gemm<<<dim3(2 + H_ / 64, (B_ * R_) / 64), 256, 0, stream>>>(
            px, Wq, bq, Wk, bk, Wv, bv, q, kk, vv);
        attn_scores<<<B_ * R_, 64, 0, stream>>>(q, kk, preS, alpha);
        attn_z<0><<<B_ * R_, 256, 0, stream>>>(alpha, vv, zs, nullptr);

        for (int b = 0; b < B_; ++b) {
            const float* xb = x + (size_t)b * L_ * C_;
            gemm64<float, float, float, 1, 0><<<dim3(H_ / 64, L_ / 64), 256, 0, stream>>>(
                xb, Wu, bu, nullptr, (const float*)nullptr, nullptr, gate_b, H_, C_, 0);
            gemm64<float, float, bf16, 0, 3><<<dim3(H_ / 64, L_ / 64), 256, 0, stream>>>(
                pAR + (size_t)b * L_ * R_, zs + (size_t)b * R_ * H_,
                nullptr, nullptr, gate_b, nullptr, gate_b, H_, R_, 0);
            gemm64<bf16, float, float, 0, 2><<<dim3(C_ / 64, L_ / 64), 256, 0, stream>>>(
                gate_b, Wo, bo, nullptr, xb, nullptr, y_b, C_, H_, 0);
            layernorm<<<L_, 256, 0, stream>>>(y_b, gamma, beta, out + (size_t)b * L_ * C_);
        }
    }
}

// Round 9
// 329.157 us; speedup vs baseline: 1.3753x; 1.1025x over previous
//
#include <hip/hip_runtime.h>
#include <hip/hip_bf16.h>

// Problem constants
constexpr int B_ = 8;
constexpr int L_ = 2048;
constexpr int C_ = 512;
constexpr int R_ = 64;
constexpr int DK_ = 64;
constexpr int H_ = 1024;   // 2*C
constexpr int M_ = B_ * L_;  // 16384
constexpr float NEG_ = -32767.0f;

__device__ __forceinline__ float toF(float x) { return x; }
__device__ __forceinline__ float toF(__hip_bfloat16 x) { return __bfloat162float(x); }
__device__ __forceinline__ float siluf(float v) { return v / (1.0f + __expf(-v)); }
__device__ __forceinline__ ushort bfbits(float f) {
    __hip_bfloat16 h = __float2bfloat16(f);
    union { __hip_bfloat16 h; ushort u; } cv; cv.h = h; return cv.u;
}
__device__ __forceinline__ float bf2f(ushort u) {
    union { uint u; float f; } cv; cv.u = (uint)u << 16; return cv.f;
}

typedef __attribute__((ext_vector_type(8))) short bf16x8;   // 8 bf16 (4 VGPRs)
typedef __attribute__((ext_vector_type(4))) float f32x4;    // 4 fp32 acc

#define GLOBAL_AS __attribute__((address_space(1)))
#define LDS_AS    __attribute__((address_space(3)))
__device__ __forceinline__ void glds16(const ushort* g, ushort* l) {
    __builtin_amdgcn_global_load_lds((const GLOBAL_AS void*)g, (LDS_AS void*)l, 16, 0, 0);
}

// ---------------------------------------------------------------------------
// MFMA bf16 GEMM, 128x128 tile, BK=32, 4 waves (2x2 of 64x64),
// mfma_f32_16x16x32_bf16, 4x4 subtiles/wave.
// ONE-BARRIER ping-pong K-loop with global_load_lds width=16:
//   prologue glds(buf0) ; loop { barrier (drains prefetch issued a full
//   compute-phase earlier) ; glds(other buf, k+32) ; ds_read+MFMA(cur) }
// LDS tiles unpadded [128][32] bf16 (wave-uniform base + lane*16 contract).
// XCD swizzle: block i -> xcd i&7; per-XCD m-major, n fastest.
// EPI 0: silu(acc+bias[n])                  -> bf16
// EPI 1: acc+bias[n]; mask[row]==0 -> NEG   -> fp32 pScore[M,R] AND
//        fp32 pScoreT[B,R,L] (outF2), Ndim=64 col-guarded
// EPI 2: acc+bias[n]+residF (fp32)          -> bf16
// EPI 3: acc*residB (bf16, in-place ok)     -> bf16 (no bias)
// bBatch: if nonzero, Bt += (m0/L_)*bBatch (batched B, expand GEMM).
// ---------------------------------------------------------------------------
template <int EPI>
__global__ __launch_bounds__(256) void mfma_gemm5(
    const ushort* __restrict__ A, const ushort* __restrict__ Bt,
    const float* __restrict__ bias,
    const float* __restrict__ residF, const ushort* __restrict__ residB,
    const int* __restrict__ mask,
    ushort* __restrict__ outB, float* __restrict__ outF, float* __restrict__ outF2,
    int Ndim, int Kdim, int gridN, long bBatch)
{
    __shared__ ushort As[2][128 * 32];   // 2 x 8 KB ping-pong
    __shared__ ushort Bs[2][128 * 32];

    const int i = blockIdx.x;
    const int G = gridDim.x >> 3;        // blocks per XCD (grid % 8 == 0)
    const int gi = (i & 7) * G + (i >> 3);
    const int nt = gi % gridN, mt = gi / gridN;
    const int m0 = mt * 128, n0 = nt * 128;

    const int tid = threadIdx.x;
    const int lane = tid & 63, w = tid >> 6;
    const int wm = (w & 1) * 64, wn = (w >> 1) * 64;
    const int lr = lane & 15, lq = lane >> 4;

    // staging: wave w stages row-segments s0=2w, s1=2w+1 (16 rows each);
    // lane -> row s*16 + (lane>>2), col (lane&3)*8  => LDS offset lane*16 B.
    const int sr = lane >> 2;
    const int sc = (lane & 3) * 8;
    const int s0 = w * 2, s1 = w * 2 + 1;

    const ushort* Bp = Bt + (bBatch ? (long)(m0 / L_) * bBatch : 0);
    int br0 = n0 + s0 * 16 + sr; if (br0 >= Ndim) br0 = Ndim - 1;   // clamp (N<128)
    int br1 = n0 + s1 * 16 + sr; if (br1 >= Ndim) br1 = Ndim - 1;
    const ushort* a0p = A  + (size_t)(m0 + s0 * 16 + sr) * Kdim + sc;
    const ushort* a1p = A  + (size_t)(m0 + s1 * 16 + sr) * Kdim + sc;
    const ushort* b0p = Bp + (size_t)br0 * Kdim + sc;
    const ushort* b1p = Bp + (size_t)br1 * Kdim + sc;
    const int lo0 = s0 * 512 + lane * 8;
    const int lo1 = s1 * 512 + lane * 8;

    f32x4 acc[4][4];
#pragma unroll
    for (int a = 0; a < 4; ++a)
#pragma unroll
        for (int b = 0; b < 4; ++b) acc[a][b] = (f32x4){0.f, 0.f, 0.f, 0.f};

    // prologue: stage k=0 into buf 0
    glds16(a0p, &As[0][lo0]);
    glds16(a1p, &As[0][lo1]);
    glds16(b0p, &Bs[0][lo0]);
    glds16(b1p, &Bs[0][lo1]);

    int cur = 0;
    for (int k0 = 0; k0 < Kdim; k0 += 32) {
        __syncthreads();              // drains prefetch (issued a compute-phase ago)
        if (k0 + 32 < Kdim) {         // prefetch next into other buffer
            const int nx = cur ^ 1;
            glds16(a0p + k0 + 32, &As[nx][lo0]);
            glds16(a1p + k0 + 32, &As[nx][lo1]);
            glds16(b0p + k0 + 32, &Bs[nx][lo0]);
            glds16(b1p + k0 + 32, &Bs[nx][lo1]);
        }
        bf16x8 af[4], bf[4];
#pragma unroll
        for (int a = 0; a < 4; ++a)
            af[a] = *(const bf16x8*)&As[cur][(wm + a * 16 + lr) * 32 + lq * 8];
#pragma unroll
        for (int b = 0; b < 4; ++b)
            bf[b] = *(const bf16x8*)&Bs[cur][(wn + b * 16 + lr) * 32 + lq * 8];
#pragma unroll
        for (int a = 0; a < 4; ++a)
#pragma unroll
            for (int b = 0; b < 4; ++b)
                acc[a][b] = __builtin_amdgcn_mfma_f32_16x16x32_bf16(af[a], bf[b], acc[a][b], 0, 0, 0);
        cur ^= 1;
    }

#pragma unroll
    for (int a = 0; a < 4; ++a) {
#pragma unroll
        for (int b = 0; b < 4; ++b) {
            const int col = n0 + wn + b * 16 + lr;
            if (col < Ndim) {
                const float bn = (EPI == 3) ? 0.f : bias[col];
#pragma unroll
                for (int r = 0; r < 4; ++r) {
                    const int row = m0 + wm + a * 16 + lq * 4 + r;
                    float v = acc[a][b][r];
                    if (EPI == 0) {
                        v = siluf(v + bn);
                        outB[(size_t)row * Ndim + col] = bfbits(v);
                    } else if (EPI == 1) {
                        v += bn;
                        if (mask[row] == 0) v = NEG_;
                        outF[(size_t)row * Ndim + col] = v;
                        const int bb = row >> 11, ll = row & (L_ - 1);
                        outF2[((size_t)bb * R_ + col) * L_ + ll] = v;
                    } else if (EPI == 2) {
                        v += bn + residF[(size_t)row * Ndim + col];
                        outB[(size_t)row * Ndim + col] = bfbits(v);
                    } else {
                        v *= bf2f(residB[(size_t)row * Ndim + col]);
                        outB[(size_t)row * Ndim + col] = bfbits(v);
                    }
                }
            }
        }
    }
}

// x fp32 -> bf16, 4 elems/thread
__global__ __launch_bounds__(256) void f32_to_bf16_k(const float* __restrict__ in,
                                                     ushort* __restrict__ out)
{
    const size_t i = ((size_t)blockIdx.x * 256 + threadIdx.x) * 4;
    const float4 v = *(const float4*)(in + i);
    ushort4 o;
    o.x = bfbits(v.x); o.y = bfbits(v.y); o.z = bfbits(v.z); o.w = bfbits(v.w);
    *(ushort4*)(out + i) = o;
}

// W[K,N] fp32 -> Wt[N,K] bf16 (32x32 LDS tiles)
__global__ __launch_bounds__(256) void transpose_to_bf16(
    const float* __restrict__ W, ushort* __restrict__ Wt, int K, int N)
{
    __shared__ float tile[32][33];
    const int tx = threadIdx.x & 31, ty = threadIdx.x >> 5;   // 32x8
    const int n0 = blockIdx.x * 32, k0 = blockIdx.y * 32;
#pragma unroll
    for (int i = 0; i < 32; i += 8)
        tile[ty + i][tx] = W[(size_t)(k0 + ty + i) * N + n0 + tx];
    __syncthreads();
#pragma unroll
    for (int i = 0; i < 32; i += 8)
        Wt[(size_t)(n0 + ty + i) * K + k0 + tx] = bfbits(tile[tx][ty + i]);
}

// coalesced softmax over L on pScoreT[B,R,L] rows -> pALT[B,R,L] bf16
__global__ __launch_bounds__(256) void softmaxL2(const float* __restrict__ pScoreT,
                                                 ushort* __restrict__ pALT)
{
    const size_t br = blockIdx.x;
    const float* row = pScoreT + br * L_;
    ushort* orow = pALT + br * L_;
    const int t = threadIdx.x;
    __shared__ float red[256];

    float v[8];
    float mx = -3.4e38f;
#pragma unroll
    for (int j = 0; j < 8; ++j) { v[j] = row[t + j * 256]; mx = fmaxf(mx, v[j]); }
    red[t] = mx; __syncthreads();
    for (int s = 128; s > 0; s >>= 1) { if (t < s) red[t] = fmaxf(red[t], red[t + s]); __syncthreads(); }
    mx = red[0]; __syncthreads();

    float e[8], sum = 0.f;
#pragma unroll
    for (int j = 0; j < 8; ++j) { e[j] = __expf(v[j] - mx); sum += e[j]; }
    red[t] = sum; __syncthreads();
    for (int s = 128; s > 0; s >>= 1) { if (t < s) red[t] += red[t + s]; __syncthreads(); }
    const float inv = 1.0f / red[0];
#pragma unroll
    for (int j = 0; j < 8; ++j) orow[t + j * 256] = bfbits(e[j] * inv);
}

// softmax over r (axis=-1). One wave per row m. OUT=0: fp32, OUT=1: bf16 bits.
template <int OUT>
__global__ __launch_bounds__(64) void softmaxR(const float* __restrict__ pScore,
                                               float* __restrict__ outF,
                                               ushort* __restrict__ outU)
{
    const size_t m = blockIdx.x;
    const int t = threadIdx.x;
    float v = pScore[m * R_ + t];
    float mx = v;
#pragma unroll
    for (int o = 32; o > 0; o >>= 1) mx = fmaxf(mx, __shfl_xor(mx, o, 64));
    float e = __expf(v - mx);
    float s = e;
#pragma unroll
    for (int o = 32; o > 0; o >>= 1) s += __shfl_xor(s, o, 64);
    if (OUT == 0) outF[m * R_ + t] = e / s;
    else          outU[m * R_ + t] = bfbits(e / s);
}

// compress K-split: parts[ks][b][r][c] = sum_{l in chunk} pALT[b][r][l]*x16[b][l][c]
__global__ __launch_bounds__(256) void compress_part2(
    const ushort* __restrict__ pALT, const ushort* __restrict__ x16,
    float* __restrict__ parts)
{
    __shared__ float As[16][64];
    __shared__ float Bs[16][64];
    const int tid = threadIdx.x;
    const int tx = tid & 15, ty = tid >> 4;
    const int n0 = blockIdx.x * 64;
    const int ks = blockIdx.y;
    const int b  = blockIdx.z;
    const ushort* paT = pALT + (size_t)b * R_ * L_;
    const ushort* xb  = x16 + (size_t)b * L_ * C_;
    float acc[4][4] = {};
    const int kbeg = ks * (L_ / 4), kend = kbeg + L_ / 4;
    for (int k0 = kbeg; k0 < kend; k0 += 16) {
#pragma unroll
        for (int s = 0; s < 4; ++s) {
            int idx = tid + s * 256;
            int m = idx >> 4, kk = idx & 15;       // A^T tile: [m][k] row-major reads
            As[kk][m] = bf2f(paT[(size_t)m * L_ + k0 + kk]);
        }
#pragma unroll
        for (int s = 0; s < 4; ++s) {
            int idx = tid + s * 256;
            int kk = idx >> 6, n = idx & 63;
            Bs[kk][n] = bf2f(xb[(size_t)(k0 + kk) * C_ + n0 + n]);
        }
        __syncthreads();
#pragma unroll
        for (int kk = 0; kk < 16; ++kk) {
            float av[4], bv[4];
            *(float4*)av = *(const float4*)&As[kk][ty * 4];
            *(float4*)bv = *(const float4*)&Bs[kk][tx * 4];
#pragma unroll
            for (int i = 0; i < 4; ++i)
#pragma unroll
                for (int j = 0; j < 4; ++j) acc[i][j] += av[i] * bv[j];
        }
        __syncthreads();
    }
#pragma unroll
    for (int i = 0; i < 4; ++i)
#pragma unroll
        for (int j = 0; j < 4; ++j)
            parts[((((size_t)ks * B_ + b) * R_) + ty * 4 + i) * C_ + n0 + tx * 4 + j] = acc[i][j];
}

__global__ __launch_bounds__(256) void compress_reduce(const float* __restrict__ parts,
                                                       float* __restrict__ px)
{
    const size_t i = (size_t)blockIdx.x * 256 + threadIdx.x;
    constexpr size_t S = (size_t)B_ * R_ * C_;
    px[i] = parts[i] + parts[i + S] + parts[i + 2 * S] + parts[i + 3 * S];
}

// qkv fused-N GEMM (SIMT)
__global__ __launch_bounds__(256) void qkv_gemm(
    const float* __restrict__ px,
    const float* __restrict__ Wq, const float* __restrict__ bq,
    const float* __restrict__ Wk, const float* __restrict__ bk,
    const float* __restrict__ Wv, const float* __restrict__ bv,
    float* __restrict__ q, float* __restrict__ k, float* __restrict__ v)
{
    __shared__ float As[16][68];
    __shared__ float Bs[16][64];
    const int tid = threadIdx.x;
    const int tx = tid & 15, ty = tid >> 4;
    const int bx = blockIdx.x;
    const int m0 = blockIdx.y * 64;
    const float* W; const float* bias; float* dst; int Nloc, ncol0;
    if (bx == 0)      { W = Wq; bias = bq; dst = q; Nloc = 64;   ncol0 = 0; }
    else if (bx == 1) { W = Wk; bias = bk; dst = k; Nloc = 64;   ncol0 = 0; }
    else              { W = Wv; bias = bv; dst = v; Nloc = H_;   ncol0 = (bx - 2) * 64; }

    float acc[4][4] = {};
    for (int k0 = 0; k0 < C_; k0 += 16) {
#pragma unroll
        for (int s = 0; s < 4; ++s) {
            int idx = tid + s * 256;
            int am = idx >> 4, ak = idx & 15;
            As[ak][am] = px[(size_t)(m0 + am) * C_ + k0 + ak];
        }
#pragma unroll
        for (int s = 0; s < 4; ++s) {
            int idx = tid + s * 256;
            int kk = idx >> 6, bn = idx & 63;
            Bs[kk][bn] = W[(size_t)(k0 + kk) * Nloc + ncol0 + bn];
        }
        __syncthreads();
#pragma unroll
        for (int kk = 0; kk < 16; ++kk) {
            float av[4], bv4[4];
            *(float4*)av = *(const float4*)&As[kk][ty * 4];
            *(float4*)bv4 = *(const float4*)&Bs[kk][tx * 4];
#pragma unroll
            for (int i = 0; i < 4; ++i)
#pragma unroll
                for (int j = 0; j < 4; ++j) acc[i][j] += av[i] * bv4[j];
        }
        __syncthreads();
    }
#pragma unroll
    for (int i = 0; i < 4; ++i) {
        int m = m0 + ty * 4 + i;
#pragma unroll
        for (int j = 0; j < 4; ++j) {
            int n = ncol0 + tx * 4 + j;
            dst[(size_t)m * Nloc + n] = siluf(acc[i][j] + bias[n]);
        }
    }
}

// fused scores+softmax+z: one block per (b,r); wave0 does scores, all do z.
__global__ __launch_bounds__(256) void attn_fused(
    const float* __restrict__ q, const float* __restrict__ k,
    const float* __restrict__ preS, const float* __restrict__ v,
    ushort* __restrict__ zsT)
{
    const int b = blockIdx.x >> 6, r = blockIdx.x & 63;
    const int t = threadIdx.x;
    __shared__ float al[R_];
    if (t < 64) {
        const float* qr = q + ((size_t)b * R_ + r) * DK_;
        const float* ks = k + ((size_t)b * R_ + t) * DK_;
        float acc = 0.f;
#pragma unroll
        for (int d = 0; d < DK_; ++d) acc += qr[d] * ks[d];
        acc = acc * 0.125f + preS[((size_t)b * R_ + r) * R_ + t];
        float mx = acc;
#pragma unroll
        for (int o = 32; o > 0; o >>= 1) mx = fmaxf(mx, __shfl_xor(mx, o, 64));
        float e = __expf(acc - mx);
        float sm = e;
#pragma unroll
        for (int o = 32; o > 0; o >>= 1) sm += __shfl_xor(sm, o, 64);
        al[t] = e / sm;
    }
    __syncthreads();
    float acc[4] = {};
    for (int s = 0; s < R_; ++s) {
        const float a = al[s];
        const float* vr = v + ((size_t)b * R_ + s) * H_;
#pragma unroll
        for (int j = 0; j < 4; ++j) acc[j] += a * vr[t + j * 256];
    }
#pragma unroll
    for (int j = 0; j < 4; ++j) {
        const int h = t + j * 256;
        zsT[((size_t)b * H_ + h) * R_ + r] = bfbits(acc[j]);
    }
}

// Row layernorm of bf16 y -> fp32 out
__global__ __launch_bounds__(256) void layernorm(const __hip_bfloat16* __restrict__ y,
                                                 const float* __restrict__ gamma,
                                                 const float* __restrict__ beta,
                                                 float* __restrict__ out)
{
    const size_t m = blockIdx.x;
    const int t = threadIdx.x;
    const __hip_bfloat16* yr = y + m * C_;
    float v0 = __bfloat162float(yr[t]), v1 = __bfloat162float(yr[t + 256]);
    __shared__ float rs[256], rq[256];
    rs[t] = v0 + v1;
    rq[t] = v0 * v0 + v1 * v1;
    __syncthreads();
    for (int o = 128; o > 0; o >>= 1) {
        if (t < o) { rs[t] += rs[t + o]; rq[t] += rq[t + o]; }
        __syncthreads();
    }
    const float mu = rs[0] * (1.0f / C_);
    const float var = rq[0] * (1.0f / C_) - mu * mu;
    const float inv = rsqrtf(var + 1e-5f);
    out[m * C_ + t] = (v0 - mu) * inv * gamma[t] + beta[t];
    out[m * C_ + t + 256] = (v1 - mu) * inv * gamma[t + 256] + beta[t + 256];
}

// ---- compact-path SIMT kernels (dead in practice, kept for safety) ----
template <typename AT, typename BT, typename RT, int ACT, int EPI>
__global__ __launch_bounds__(256) void gemm64(
    const AT* __restrict__ A, const BT* __restrict__ Bw,
    const float* __restrict__ bias, const int* __restrict__ mask,
    const RT* resid, float* __restrict__ outF, __hip_bfloat16* outB,
    int Ndim, int Kdim, long bBatchStride)
{
    __shared__ float As[16][68];
    __shared__ float Bs[16][64];
    const int tid = threadIdx.x;
    const int tx = tid & 15, ty = tid >> 4;
    const int n0 = blockIdx.x * 64, m0 = blockIdx.y * 64;
    const BT* Bp = Bw + (bBatchStride ? (long)(m0 / L_) * bBatchStride : 0);
    float acc[4][4] = {};
    for (int k0 = 0; k0 < Kdim; k0 += 16) {
#pragma unroll
        for (int s = 0; s < 4; ++s) {
            int idx = tid + s * 256;
            int am = idx >> 4, ak = idx & 15;
            As[ak][am] = toF(A[(size_t)(m0 + am) * Kdim + k0 + ak]);
        }
#pragma unroll
        for (int s = 0; s < 4; ++s) {
            int idx = tid + s * 256;
            int bk = idx >> 6, bn = idx & 63;
            Bs[bk][bn] = toF(Bp[(size_t)(k0 + bk) * Ndim + n0 + bn]);
        }
        __syncthreads();
#pragma unroll
        for (int kk = 0; kk < 16; ++kk) {
            float av[4], bv[4];
            *(float4*)av = *(const float4*)&As[kk][ty * 4];
            *(float4*)bv = *(const float4*)&Bs[kk][tx * 4];
#pragma unroll
            for (int i = 0; i < 4; ++i)
#pragma unroll
                for (int j = 0; j < 4; ++j) acc[i][j] += av[i] * bv[j];
        }
        __syncthreads();
    }
#pragma unroll
    for (int i = 0; i < 4; ++i) {
        int m = m0 + ty * 4 + i;
#pragma unroll
        for (int j = 0; j < 4; ++j) {
            int n = n0 + tx * 4 + j;
            float val = acc[i][j];
            if (EPI != 3) val += bias[n];
            if (ACT) val = siluf(val);
            if (EPI == 0) outB[(size_t)m * Ndim + n] = __float2bfloat16(val);
            else if (EPI == 1) { if (mask[m] == 0) val = NEG_; outF[(size_t)m * Ndim + n] = val; }
            else if (EPI == 2) { val += toF(resid[(size_t)m * Ndim + n]); outB[(size_t)m * Ndim + n] = __float2bfloat16(val); }
            else { val *= toF(resid[(size_t)m * Ndim + n]); outB[(size_t)m * Ndim + n] = __float2bfloat16(val); }
        }
    }
}

__global__ __launch_bounds__(256) void softmaxL(const float* __restrict__ pScore,
                                                float* __restrict__ pAlpha)
{
    const int b = blockIdx.x >> 6, r = blockIdx.x & 63;
    const int t = threadIdx.x;
    const float* base = pScore + (size_t)b * L_ * R_ + r;
    float* out = pAlpha + (size_t)b * L_ * R_ + r;
    __shared__ float red[256];
    float mx = -3.4e38f;
    for (int l = t; l < L_; l += 256) mx = fmaxf(mx, base[(size_t)l * R_]);
    red[t] = mx; __syncthreads();
    for (int s = 128; s > 0; s >>= 1) { if (t < s) red[t] = fmaxf(red[t], red[t + s]); __syncthreads(); }
    mx = red[0]; __syncthreads();
    float sum = 0.f;
    for (int l = t; l < L_; l += 256) {
        float e = __expf(base[(size_t)l * R_] - mx);
        out[(size_t)l * R_] = e; sum += e;
    }
    red[t] = sum; __syncthreads();
    for (int s = 128; s > 0; s >>= 1) { if (t < s) red[t] += red[t + s]; __syncthreads(); }
    const float inv = 1.0f / red[0];
    for (int l = t; l < L_; l += 256) out[(size_t)l * R_] *= inv;
}

__global__ __launch_bounds__(256) void compress_part(
    const float* __restrict__ pAlpha, const float* __restrict__ x,
    float* __restrict__ parts)
{
    __shared__ float As[16][64];
    __shared__ float Bs[16][64];
    const int tid = threadIdx.x;
    const int tx = tid & 15, ty = tid >> 4;
    const int n0 = blockIdx.x * 64;
    const int ks = blockIdx.y;
    const int b  = blockIdx.z;
    const float* pa = pAlpha + (size_t)b * L_ * R_;
    const float* xb = x + (size_t)b * L_ * C_;
    float acc[4][4] = {};
    const int kbeg = ks * (L_ / 4), kend = kbeg + L_ / 4;
    for (int k0 = kbeg; k0 < kend; k0 += 16) {
#pragma unroll
        for (int s = 0; s < 4; ++s) {
            int idx = tid + s * 256;
            int kk = idx >> 6, m = idx & 63;
            As[kk][m] = pa[(size_t)(k0 + kk) * R_ + m];
        }
#pragma unroll
        for (int s = 0; s < 4; ++s) {
            int idx = tid + s * 256;
            int kk = idx >> 6, n = idx & 63;
            Bs[kk][n] = xb[(size_t)(k0 + kk) * C_ + n0 + n];
        }
        __syncthreads();
#pragma unroll
        for (int kk = 0; kk < 16; ++kk) {
            float av[4], bv[4];
            *(float4*)av = *(const float4*)&As[kk][ty * 4];
            *(float4*)bv = *(const float4*)&Bs[kk][tx * 4];
#pragma unroll
            for (int i = 0; i < 4; ++i)
#pragma unroll
                for (int j = 0; j < 4; ++j) acc[i][j] += av[i] * bv[j];
        }
        __syncthreads();
    }
#pragma unroll
    for (int i = 0; i < 4; ++i)
#pragma unroll
        for (int j = 0; j < 4; ++j)
            parts[((((size_t)ks * B_ + b) * R_) + ty * 4 + i) * C_ + n0 + tx * 4 + j] = acc[i][j];
}

template <int MODE>
__global__ __launch_bounds__(256) void attn_z(const float* __restrict__ alpha,
                                              const float* __restrict__ v,
                                              float* __restrict__ zsF,
                                              ushort* __restrict__ zsT)
{
    const int b = blockIdx.x >> 6, r = blockIdx.x & 63;
    const int t = threadIdx.x;
    __shared__ float al[R_];
    if (t < R_) al[t] = alpha[((size_t)b * R_ + r) * R_ + t];
    __syncthreads();
    float acc[4] = {};
    for (int s = 0; s < R_; ++s) {
        float a = al[s];
        const float* vr = v + ((size_t)b * R_ + s) * H_;
#pragma unroll
        for (int j = 0; j < 4; ++j) acc[j] += a * vr[t + j * 256];
    }
#pragma unroll
    for (int j = 0; j < 4; ++j) {
        const int h = t + j * 256;
        if (MODE == 0) zsF[((size_t)b * R_ + r) * H_ + h] = acc[j];
        else           zsT[((size_t)b * H_ + h) * R_ + r] = bfbits(acc[j]);
    }
}

__global__ __launch_bounds__(64) void attn_scores(
    const float* __restrict__ q, const float* __restrict__ k,
    const float* __restrict__ preS, float* __restrict__ alpha)
{
    const int b = blockIdx.x >> 6, r = blockIdx.x & 63;
    const int s = threadIdx.x;
    const float* qr = q + ((size_t)b * R_ + r) * DK_;
    const float* ks = k + ((size_t)b * R_ + s) * DK_;
    float acc = 0.f;
#pragma unroll
    for (int d = 0; d < DK_; ++d) acc += qr[d] * ks[d];
    acc = acc * 0.125f + preS[((size_t)b * R_ + r) * R_ + s];
    float mx = acc;
#pragma unroll
    for (int o = 32; o > 0; o >>= 1) mx = fmaxf(mx, __shfl_xor(mx, o, 64));
    float e = __expf(acc - mx);
    float sm = e;
#pragma unroll
    for (int o = 32; o > 0; o >>= 1) sm += __shfl_xor(sm, o, 64);
    alpha[((size_t)b * R_ + r) * R_ + s] = e / sm;
}

extern "C" void kernel_launch(void* const* d_in, const int* in_sizes, int n_in,
                              void* d_out, int out_size, void* d_ws, size_t ws_size,
                              hipStream_t stream)
{
    using bf16 = __hip_bfloat16;
    const float* x      = (const float*)d_in[0];
    const int*  maskPAD = (const int*)d_in[1];
    const float* preS   = (const float*)d_in[2];
    const float* Wp     = (const float*)d_in[3];
    const float* bp     = (const float*)d_in[4];
    const float* Wq     = (const float*)d_in[5];
    const float* bq     = (const float*)d_in[6];
    const float* Wk     = (const float*)d_in[7];
    const float* bk     = (const float*)d_in[8];
    const float* Wv     = (const float*)d_in[9];
    const float* bv     = (const float*)d_in[10];
    const float* Wu     = (const float*)d_in[11];
    const float* bu     = (const float*)d_in[12];
    const float* Wo     = (const float*)d_in[13];
    const float* bo     = (const float*)d_in[14];
    const float* gamma  = (const float*)d_in[15];
    const float* beta   = (const float*)d_in[16];
    float* out          = (float*)d_out;

    char* ws = (char*)d_ws;
    const bool bigWS = ws_size >= (size_t)52 * 1024 * 1024;  // proven taken (rounds 4-8)

    if (bigWS) {
        // layout (51.4 MiB): gate 33.5 MB | pool 18.2 MB | Wut | Wot | Wpt
        bf16* gate = (bf16*)ws;                                 // M*H bf16 (zg in-place later)
        char* pool = ws + (size_t)M_ * H_ * 2;
        // pool plan (16.25 MB used of 18.2):
        float* pScore  = (float*)pool;                          // M*R f32 (4 MB); later parts
        float* pScoreT = pScore + (size_t)M_ * R_;              // B*R*L f32 (4 MB); parts tail
        ushort* pALT   = (ushort*)(pScoreT + (size_t)B_ * R_ * L_);  // B*R*L bf16 (2 MB)
        ushort* pAR16  = pALT + (size_t)B_ * R_ * L_;           // M*R bf16 (2 MB)
        float* px      = (float*)(pAR16 + (size_t)M_ * R_);     // B*R*C f32 (1 MB)
        float* q       = px + (size_t)B_ * R_ * C_;             // 128 KB
        float* kk      = q + (size_t)B_ * R_ * DK_;             // 128 KB
        float* vv      = kk + (size_t)B_ * R_ * DK_;            // B*R*H f32 (2 MB)
        ushort* zsT16  = (ushort*)(vv + (size_t)B_ * R_ * H_);  // B*H*R bf16 (1 MB)
        float* parts   = pScore;                                // 4 MB (pScore+pScoreT dead)
        bf16*  y       = (bf16*)pool;                           // pre-LN y (16.8 MB), all pool dead
        ushort* Wut    = (ushort*)(pool + 18221568);            // [H, C] bf16
        ushort* Wot    = Wut + (size_t)C_ * H_;                 // [C, H] bf16
        ushort* Wpt    = Wot + (size_t)C_ * H_;                 // [R, C] bf16
        ushort* x16    = (ushort*)d_out;                        // [M, C] bf16 (dead before LN)

        f32_to_bf16_k<<<(M_ * C_) / 1024, 256, 0, stream>>>(x, x16);
        transpose_to_bf16<<<dim3(H_ / 32, C_ / 32), 256, 0, stream>>>(Wu, Wut, C_, H_);
        transpose_to_bf16<<<dim3(C_ / 32, H_ / 32), 256, 0, stream>>>(Wo, Wot, H_, C_);
        transpose_to_bf16<<<dim3(R_ / 32, C_ / 32), 256, 0, stream>>>(Wp, Wpt, C_, R_);

        // 1) gate = silu(x @ Wu + bu)
        mfma_gemm5<0><<<(H_ / 128) * (M_ / 128), 256, 0, stream>>>(
            x16, Wut, bu, nullptr, nullptr, nullptr, (ushort*)gate, nullptr, nullptr,
            H_, C_, H_ / 128, 0);
        // 2) pScore (+ transposed copy), masked
        mfma_gemm5<1><<<M_ / 128, 256, 0, stream>>>(
            x16, Wpt, bp, nullptr, nullptr, maskPAD, nullptr, pScore, pScoreT,
            R_, C_, 1, 0);
        softmaxL2<<<B_ * R_, 256, 0, stream>>>(pScoreT, pALT);
        softmaxR<1><<<M_, 64, 0, stream>>>(pScore, nullptr, pAR16);
        compress_part2<<<dim3(C_ / 64, 4, B_), 256, 0, stream>>>(pALT, x16, parts);
        compress_reduce<<<(B_ * R_ * C_) / 256, 256, 0, stream>>>(parts, px);
        qkv_gemm<<<dim3(2 + H_ / 64, (B_ * R_) / 64), 256, 0, stream>>>(
            px, Wq, bq, Wk, bk, Wv, bv, q, kk, vv);
        attn_fused<<<B_ * R_, 256, 0, stream>>>(q, kk, preS, vv, zsT16);
        // zg = gate * (pAR @ zs)  [K=64, batched B, in-place]
        mfma_gemm5<3><<<(H_ / 128) * (M_ / 128), 256, 0, stream>>>(
            pAR16, zsT16, nullptr, nullptr, (ushort*)gate, nullptr, (ushort*)gate,
            nullptr, nullptr, H_, R_, H_ / 128, (long)H_ * R_);
        // y = x + zg @ Wo + bo
        mfma_gemm5<2><<<(C_ / 128) * (M_ / 128), 256, 0, stream>>>(
            (ushort*)gate, Wot, bo, x, nullptr, nullptr, (ushort*)y, nullptr, nullptr,
            C_, H_, C_ / 128, 0);
        layernorm<<<M_, 256, 0, stream>>>(y, gamma, beta, out);
    } else {
        // ---- Compact plan (~23.4 MiB), SIMT per-batch (dead in practice) ----
        float* pScore = (float*)ws;
        float* pAL   = pScore + (size_t)M_ * R_;
        float* pAR   = pAL    + (size_t)M_ * R_;
        float* px    = pAR    + (size_t)M_ * R_;
        float* q     = px     + (size_t)B_ * R_ * C_;
        float* kk    = q      + (size_t)B_ * R_ * DK_;
        float* vv    = kk     + (size_t)B_ * R_ * DK_;
        float* alpha = vv     + (size_t)B_ * R_ * H_;
        float* zs    = alpha  + (size_t)B_ * R_ * R_;
        bf16* gate_b = (bf16*)(zs + (size_t)B_ * R_ * H_);
        bf16* y_b    = (bf16*)((char*)gate_b + (size_t)L_ * H_ * 2);

        gemm64<float, float, float, 0, 1><<<dim3(R_ / 64, M_ / 64), 256, 0, stream>>>(
            x, Wp, bp, maskPAD, (const float*)nullptr, pScore, nullptr, R_, C_, 0);
        softmaxL<<<B_ * R_, 256, 0, stream>>>(pScore, pAL);
        softmaxR<0><<<M_, 64, 0, stream>>>(pScore, pAR, nullptr);
        compress_part<<<dim3(C_ / 64, 4, B_), 256, 0, stream>>>(pAL, x, pScore);
        compress_reduce<<<(B_ * R_ * C_) / 256, 256, 0, stream>>>(pScore, px);
        qkv_gemm<<<dim3(2 + H_ / 64, (B_ * R_) / 64), 256, 0, stream>>>(
            px, Wq, bq, Wk, bk, Wv, bv, q, kk, vv);
        attn_scores<<<B_ * R_, 64, 0, stream>>>(q, kk, preS, alpha);
        attn_z<0><<<B_ * R_, 256, 0, stream>>>(alpha, vv, zs, nullptr);

        for (int b = 0; b < B_; ++b) {
            const float* xb = x + (size_t)b * L_ * C_;
            gemm64<float, float, float, 1, 0><<<dim3(H_ / 64, L_ / 64), 256, 0, stream>>>(
                xb, Wu, bu, nullptr, (const float*)nullptr, nullptr, gate_b, H_, C_, 0);
            gemm64<float, float, bf16, 0, 3><<<dim3(H_ / 64, L_ / 64), 256, 0, stream>>>(
                pAR + (size_t)b * L_ * R_, zs + (size_t)b * R_ * H_,
                nullptr, nullptr, gate_b, nullptr, gate_b, H_, R_, 0);
            gemm64<bf16, float, float, 0, 2><<<dim3(C_ / 64, L_ / 64), 256, 0, stream>>>(
                gate_b, Wo, bo, nullptr, xb, nullptr, y_b, C_, H_, 0);
            layernorm<<<L_, 256, 0, stream>>>(y_b, gamma, beta, out + (size_t)b * L_ * C_);
        }
    }
}